// Round 11
// baseline (307.442 us; speedup 1.0000x reference)
//
#include <hip/hip_runtime.h>
#include <hip/hip_bf16.h>

#define B_SZ 64
#define T_SZ 2048
#define EPROJS 512
#define DUNITS 1024
#define ATT_DIM 320
#define NCH 10
#define KFILT 201
#define PAD 100

typedef __attribute__((ext_vector_type(8))) __bf16 bf16x8;
typedef __attribute__((ext_vector_type(4))) float f32x4;
typedef __attribute__((ext_vector_type(16))) float f32x16;
typedef __attribute__((ext_vector_type(8))) unsigned short u16x8;

__device__ __forceinline__ unsigned short f2b(float f) {
    __bf16 h = (__bf16)f;
    return __builtin_bit_cast(unsigned short, h);
}

// ---------- W_enc f32 -> bf16 ----------
__global__ void cvt_wenc(const float* __restrict__ W, unsigned short* __restrict__ out) {
    int i = (blockIdx.x * 256 + threadIdx.x) * 4;
    float4 v = *(const float4*)(W + i);
    ushort4 o;
    o.x = f2b(v.x); o.y = f2b(v.y); o.z = f2b(v.z); o.w = f2b(v.w);
    *(ushort4*)(out + i) = o;
}

// ---------- dec_feat[b][a] = dec_z[b] . W_dec[a] + b_enc[a] ----------
__global__ void dec_feat_k(const float* __restrict__ dec_z, const float* __restrict__ W_dec,
                           const float* __restrict__ b_enc, float* __restrict__ df) {
    int b = blockIdx.x;
    int a = threadIdx.x;          // 320 threads
    const float4* z = (const float4*)(dec_z + b * DUNITS);
    const float4* w = (const float4*)(W_dec + (size_t)a * DUNITS);
    float s = b_enc[a];
    #pragma unroll 4
    for (int d = 0; d < DUNITS / 4; ++d) {
        float4 zv = z[d], wv = w[d];
        s += zv.x * wv.x + zv.y * wv.y + zv.z * wv.z + zv.w * wv.w;
    }
    df[b * ATT_DIM + a] = s;
}

// ---------- att_conv[b][c][t] ----------
__global__ void conv_k(const float* __restrict__ ap, const float* __restrict__ cw,
                       float* __restrict__ out) {
    int b = blockIdx.x, c = blockIdx.y;
    __shared__ float s_ap[T_SZ];
    __shared__ float s_cw[KFILT];
    int tid = threadIdx.x;
    for (int i = tid; i < T_SZ; i += 256) s_ap[i] = ap[b * T_SZ + i];
    for (int i = tid; i < KFILT; i += 256) s_cw[i] = cw[c * KFILT + i];
    __syncthreads();
    for (int j = 0; j < T_SZ / 256; ++j) {
        int t = tid + j * 256;
        int klo = max(0, PAD - t);
        int khi = min(KFILT, T_SZ + PAD - t);
        float s = 0.f;
        for (int k = klo; k < khi; ++k) s += s_ap[t - PAD + k] * s_cw[k];
        out[((size_t)(b * NCH + c)) * T_SZ + t] = s;
    }
}

// ---------- energy kernel: r8 mechanics + 32x32x16 MFMA (4rg x 2cg) + block skip ----------
// Per wave per chunk: 10 ds_read_b128 + 10 MFMA (vs r8: 20+20). acc = 5 x f32x16 (AGPR).
// Staging = reg -> ds_write write-late; lgkmcnt-only barrier; epilogue all-LDS (r6 lesson).
// B frag: lane holds W[col=l&31][k=(l>>5)*8+j]; C/D: col=l&31, row=(r&3)+8*(r>>2)+4*(l>>5).
__global__ __launch_bounds__(512, 1) void energy_k(
    const float* __restrict__ enc, const unsigned short* __restrict__ wbf,
    const float* __restrict__ df, const float* __restrict__ att_conv,
    const float* __restrict__ W_att, const float* __restrict__ W_g,
    const int* __restrict__ len, float* __restrict__ e_out)
{
    __shared__ unsigned short sW[2][1280 * 8];    // 2 x 20 KB, granule-major (i = g*320+wr)
    __shared__ float sDf[ATT_DIM], sWg[ATT_DIM], sWatt[ATT_DIM * NCH], sConv[NCH * 128];
    __shared__ float sE[2][128];                  // col-group partial energies

    int tid = threadIdx.x;
    int lane = tid & 63, wave = tid >> 6;         // 8 waves
    int rg = wave >> 1, cg = wave & 1;            // 4 row-groups (M=32) x 2 col-groups (N=160)
    int b = blockIdx.x >> 4;
    int t0 = (blockIdx.x & 15) << 7;              // BM = 128

    // masked-block skip: softmax masks t >= len[b] by INDEX, e content irrelevant
    if (t0 >= len[b]) return;

    int l31 = lane & 31, hi = lane >> 5;
    const float* aP = enc + ((size_t)b * T_SZ + t0 + rg * 32 + l31) * EPROJS;

    // per-thread staging coords: granules tid, tid+512, (tid+1024 if tid<256)
    int q0 = tid >> 6;        int g0 = (q0 * 205) >> 10; int wr0 = tid - g0 * 320;
    int i1 = tid + 512;  int q1 = i1 >> 6; int g1 = (q1 * 205) >> 10; int wr1 = i1 - g1 * 320;
    int i2 = tid + 1024; int q2 = i2 >> 6; int g2 = (q2 * 205) >> 10; int wr2 = i2 - g2 * 320;
    bool do2 = tid < 256;
    const unsigned short* wp0 = wbf + (size_t)wr0 * EPROJS + g0 * 8;
    const unsigned short* wp1 = wbf + (size_t)wr1 * EPROJS + g1 * 8;
    const unsigned short* wp2 = wbf + (size_t)wr2 * EPROJS + g2 * 8;

    // ---- prologue: stage chunk 0 into buffer 0; A chunk 0 into regs ----
    {
        u16x8 v0 = *(const u16x8*)wp0;
        u16x8 v1 = *(const u16x8*)wp1;
        *(u16x8*)(&sW[0][tid * 8]) = v0;
        *(u16x8*)(&sW[0][i1 * 8]) = v1;
        if (do2) {
            u16x8 v2 = *(const u16x8*)wp2;
            *(u16x8*)(&sW[0][i2 * 8]) = v2;
        }
    }
    // A: step0 k = hi*8..+8, step1 k = 16+hi*8..+8
    float4 a0 = *(const float4*)(aP + hi * 8);
    float4 a1 = *(const float4*)(aP + hi * 8 + 4);
    float4 a2 = *(const float4*)(aP + 16 + hi * 8);
    float4 a3 = *(const float4*)(aP + 16 + hi * 8 + 4);

    for (int i = tid; i < ATT_DIM; i += 512) { sDf[i] = df[b * ATT_DIM + i]; sWg[i] = W_g[i]; }
    for (int i = tid; i < ATT_DIM * NCH; i += 512) sWatt[i] = W_att[i];
    for (int i = tid; i < NCH * 128; i += 512)
        sConv[i] = att_conv[((size_t)(b * NCH + (i >> 7))) * T_SZ + t0 + (i & 127)];

    f32x16 acc[5];
    #pragma unroll
    for (int n = 0; n < 5; ++n)
        #pragma unroll
        for (int r = 0; r < 16; ++r) acc[n][r] = 0.f;

    __syncthreads();   // full drain once: chunk 0 + front matter visible

    for (int t = 0; t < 16; ++t) {
        int cur = t & 1;
        // 1) issue next chunk's W + A loads (wrap on last iter; harmless)
        int kn = ((t + 1) & 15) * 32;
        u16x8 w0 = *(const u16x8*)(wp0 + kn);
        u16x8 w1 = *(const u16x8*)(wp1 + kn);
        u16x8 w2;
        if (do2) w2 = *(const u16x8*)(wp2 + kn);
        float4 n0 = *(const float4*)(aP + kn + hi * 8);
        float4 n1 = *(const float4*)(aP + kn + hi * 8 + 4);
        float4 n2 = *(const float4*)(aP + kn + 16 + hi * 8);
        float4 n3 = *(const float4*)(aP + kn + 16 + hi * 8 + 4);

        // 2) compute chunk t from buf[cur]: 5 N-tiles x 2 k-steps of 32x32x16
        bf16x8 af0, af1;
        af0[0] = (__bf16)a0.x; af0[1] = (__bf16)a0.y; af0[2] = (__bf16)a0.z; af0[3] = (__bf16)a0.w;
        af0[4] = (__bf16)a1.x; af0[5] = (__bf16)a1.y; af0[6] = (__bf16)a1.z; af0[7] = (__bf16)a1.w;
        af1[0] = (__bf16)a2.x; af1[1] = (__bf16)a2.y; af1[2] = (__bf16)a2.z; af1[3] = (__bf16)a2.w;
        af1[4] = (__bf16)a3.x; af1[5] = (__bf16)a3.y; af1[6] = (__bf16)a3.z; af1[7] = (__bf16)a3.w;
        const unsigned short* sw = sW[cur];
        #pragma unroll
        for (int nt = 0; nt < 5; ++nt) {
            int wr = cg * 160 + nt * 32 + l31;
            bf16x8 wf0 = *(const bf16x8*)(sw + ((hi) * 320 + wr) * 8);        // k-step 0
            acc[nt] = __builtin_amdgcn_mfma_f32_32x32x16_bf16(af0, wf0, acc[nt], 0, 0, 0);
            bf16x8 wf1 = *(const bf16x8*)(sw + ((2 + hi) * 320 + wr) * 8);    // k-step 1
            acc[nt] = __builtin_amdgcn_mfma_f32_32x32x16_bf16(af1, wf1, acc[nt], 0, 0, 0);
        }

        // 3) write-late: store next chunk into the other buffer
        unsigned short* swn = (unsigned short*)sW[cur ^ 1];
        *(u16x8*)(&swn[tid * 8]) = w0;
        *(u16x8*)(&swn[i1 * 8]) = w1;
        if (do2) *(u16x8*)(&swn[i2 * 8]) = w2;
        a0 = n0; a1 = n1; a2 = n2; a3 = n3;

        // 4) my ds ops complete -> barrier (NO vmcnt drain: A loads stay in flight)
        asm volatile("s_waitcnt lgkmcnt(0)" ::: "memory");
        __builtin_amdgcn_s_barrier();
    }

    // epilogue: partial e over this col-group's 160 cols, all LDS operands
    #pragma unroll
    for (int r = 0; r < 16; ++r) {
        int tl = rg * 32 + (r & 3) + 8 * (r >> 2) + 4 * hi;
        float s = 0.f;
        #pragma unroll
        for (int nt = 0; nt < 5; ++nt) {
            int col = cg * 160 + nt * 32 + l31;
            float v = acc[nt][r] + sDf[col];
            float afeat = 0.f;
            #pragma unroll
            for (int c = 0; c < NCH; ++c) afeat += sWatt[col * NCH + c] * sConv[c * 128 + tl];
            v += afeat;
            v = fminf(fmaxf(v, -15.f), 15.f);
            float e2 = __expf(2.f * v);
            s += sWg[col] * ((e2 - 1.f) / (e2 + 1.f));
        }
        // reduce over 32 cols (lanes within half; xor<=16 stays in-half)
        s += __shfl_xor(s, 1); s += __shfl_xor(s, 2);
        s += __shfl_xor(s, 4); s += __shfl_xor(s, 8); s += __shfl_xor(s, 16);
        if (l31 == 0) sE[cg][tl] = s;
    }
    __syncthreads();
    if (tid < 128) e_out[b * T_SZ + t0 + tid] = sE[0][tid] + sE[1][tid];
}

// ---------- masked softmax over T, per b ----------
__global__ void softmax_k(const float* __restrict__ e, const int* __restrict__ len,
                          float* __restrict__ w_out) {
    int b = blockIdx.x, tid = threadIdx.x;
    int lane = tid & 63, wave = tid >> 6;
    int L = len[b];
    float ev[8];
    float m = -1e30f;
    #pragma unroll
    for (int i = 0; i < 8; ++i) {
        int t = tid + i * 256;
        float x = e[b * T_SZ + t];
        if (t >= L) x = -1e30f;
        ev[i] = x;
        m = fmaxf(m, x);
    }
    #pragma unroll
    for (int o = 32; o > 0; o >>= 1) m = fmaxf(m, __shfl_xor(m, o));
    __shared__ float sred[4];
    if (lane == 0) sred[wave] = m;
    __syncthreads();
    m = fmaxf(fmaxf(sred[0], sred[1]), fmaxf(sred[2], sred[3]));

    float ex[8];
    float sum = 0.f;
    #pragma unroll
    for (int i = 0; i < 8; ++i) { ex[i] = __expf(2.f * (ev[i] - m)); sum += ex[i]; }
    #pragma unroll
    for (int o = 32; o > 0; o >>= 1) sum += __shfl_xor(sum, o);
    __shared__ float sred2[4];
    if (lane == 0) sred2[wave] = sum;
    __syncthreads();
    sum = sred2[0] + sred2[1] + sred2[2] + sred2[3];
    float inv = 1.f / sum;
    #pragma unroll
    for (int i = 0; i < 8; ++i) {
        int t = tid + i * 256;
        w_out[b * T_SZ + t] = ex[i] * inv;
    }
}

// ---------- context partial: branchless inner loop + masked-block skip ----------
__global__ void ctx_partial_k(const float* __restrict__ enc, const float* __restrict__ w,
                              const int* __restrict__ len, float* __restrict__ part) {
    int b = blockIdx.x, tc = blockIdx.y, tid = threadIdx.x;
    int half = tid >> 7;          // 0/1: even/odd rows
    int c4 = tid & 127;           // float4 column index (128*4 = 512)
    int tb = tc * 128;
    float* po = part + ((size_t)(b * 32 + tc * 2 + half)) * EPROJS + c4 * 4;
    if (tb >= len[b]) {           // whole chunk masked: contribute exact zeros
        *(f32x4*)po = (f32x4){0.f, 0.f, 0.f, 0.f};
        return;
    }
    f32x4 s = (f32x4){0.f, 0.f, 0.f, 0.f};
    #pragma unroll 4
    for (int i = half; i < 128; i += 2) {
        float wv = w[b * T_SZ + tb + i];              // masked rows are exactly 0
        f32x4 v = *(const f32x4*)(enc + ((size_t)b * T_SZ + tb + i) * EPROJS + c4 * 4);
        s += wv * v;
    }
    *(f32x4*)po = s;
}

__global__ void ctx_reduce_k(const float* __restrict__ part, float* __restrict__ c_out) {
    int b = blockIdx.x;
    int c4 = threadIdx.x;         // 128 threads, float4 each
    f32x4 s = (f32x4){0.f, 0.f, 0.f, 0.f};
    #pragma unroll
    for (int tc = 0; tc < 32; ++tc)
        s += *(const f32x4*)(part + ((size_t)(b * 32 + tc)) * EPROJS + c4 * 4);
    *(f32x4*)(c_out + b * EPROJS + c4 * 4) = s;
}

extern "C" void kernel_launch(void* const* d_in, const int* in_sizes, int n_in,
                              void* d_out, int out_size, void* d_ws, size_t ws_size,
                              hipStream_t stream) {
    const float* enc      = (const float*)d_in[0];
    const int*   len      = (const int*)d_in[1];
    const float* dec_z    = (const float*)d_in[2];
    const float* att_prev = (const float*)d_in[3];
    const float* W_enc    = (const float*)d_in[4];
    const float* b_enc    = (const float*)d_in[5];
    const float* W_dec    = (const float*)d_in[6];
    const float* W_att    = (const float*)d_in[7];
    const float* conv_w   = (const float*)d_in[8];
    const float* W_g      = (const float*)d_in[9];
    // b_g (d_in[10]) == 0 and softmax-invariant anyway.

    char* ws = (char*)d_ws;
    size_t off = 0;
    unsigned short* wbf = (unsigned short*)(ws + off); off += (size_t)ATT_DIM * EPROJS * 2;
    float* e_buf  = (float*)(ws + off); off += (size_t)B_SZ * T_SZ * 4;
    float* dfb    = (float*)(ws + off); off += (size_t)B_SZ * ATT_DIM * 4;
    float* att_cv = (float*)(ws + off); off += (size_t)B_SZ * NCH * T_SZ * 4;
    float* part   = (float*)(ws + off); off += (size_t)B_SZ * 32 * EPROJS * 4;

    float* c_out = (float*)d_out;                    // [64][512]
    float* w_out = (float*)d_out + B_SZ * EPROJS;    // [64][2048]

    cvt_wenc<<<dim3(160), dim3(256), 0, stream>>>(W_enc, wbf);
    dec_feat_k<<<dim3(B_SZ), dim3(ATT_DIM), 0, stream>>>(dec_z, W_dec, b_enc, dfb);
    conv_k<<<dim3(B_SZ, NCH), dim3(256), 0, stream>>>(att_prev, conv_w, att_cv);
    energy_k<<<dim3(B_SZ * 16), dim3(512), 0, stream>>>(enc, wbf, dfb, att_cv, W_att, W_g, len, e_buf);
    softmax_k<<<dim3(B_SZ), dim3(256), 0, stream>>>(e_buf, len, w_out);
    ctx_partial_k<<<dim3(B_SZ, 16), dim3(256), 0, stream>>>(enc, w_out, len, part);
    ctx_reduce_k<<<dim3(B_SZ), dim3(128), 0, stream>>>(part, c_out);
}

// Round 12
// 243.803 us; speedup vs baseline: 1.2610x; 1.2610x over previous
//
#include <hip/hip_runtime.h>
#include <hip/hip_bf16.h>

#define B_SZ 64
#define T_SZ 2048
#define EPROJS 512
#define DUNITS 1024
#define ATT_DIM 320
#define NCH 10
#define KFILT 201
#define PAD 100

typedef __attribute__((ext_vector_type(8))) __bf16 bf16x8;
typedef __attribute__((ext_vector_type(4))) float f32x4;
typedef __attribute__((ext_vector_type(8))) unsigned short u16x8;

__device__ __forceinline__ unsigned short f2b(float f) {
    __bf16 h = (__bf16)f;
    return __builtin_bit_cast(unsigned short, h);
}

// ---------- W_enc f32 -> bf16 ----------
__global__ void cvt_wenc(const float* __restrict__ W, unsigned short* __restrict__ out) {
    int i = (blockIdx.x * 256 + threadIdx.x) * 4;
    float4 v = *(const float4*)(W + i);
    ushort4 o;
    o.x = f2b(v.x); o.y = f2b(v.y); o.z = f2b(v.z); o.w = f2b(v.w);
    *(ushort4*)(out + i) = o;
}

// ---------- dec_feat[b][a] = dec_z[b] . W_dec[a] + b_enc[a] ----------
__global__ void dec_feat_k(const float* __restrict__ dec_z, const float* __restrict__ W_dec,
                           const float* __restrict__ b_enc, float* __restrict__ df) {
    int b = blockIdx.x;
    int a = threadIdx.x;          // 320 threads
    const float4* z = (const float4*)(dec_z + b * DUNITS);
    const float4* w = (const float4*)(W_dec + (size_t)a * DUNITS);
    float s = b_enc[a];
    #pragma unroll 4
    for (int d = 0; d < DUNITS / 4; ++d) {
        float4 zv = z[d], wv = w[d];
        s += zv.x * wv.x + zv.y * wv.y + zv.z * wv.z + zv.w * wv.w;
    }
    df[b * ATT_DIM + a] = s;
}

// ---------- att_conv[b][c][t] ----------
__global__ void conv_k(const float* __restrict__ ap, const float* __restrict__ cw,
                       float* __restrict__ out) {
    int b = blockIdx.x, c = blockIdx.y;
    __shared__ float s_ap[T_SZ];
    __shared__ float s_cw[KFILT];
    int tid = threadIdx.x;
    for (int i = tid; i < T_SZ; i += 256) s_ap[i] = ap[b * T_SZ + i];
    for (int i = tid; i < KFILT; i += 256) s_cw[i] = cw[c * KFILT + i];
    __syncthreads();
    for (int j = 0; j < T_SZ / 256; ++j) {
        int t = tid + j * 256;
        int klo = max(0, PAD - t);
        int khi = min(KFILT, T_SZ + PAD - t);
        float s = 0.f;
        for (int k = klo; k < khi; ++k) s += s_ap[t - PAD + k] * s_cw[k];
        out[((size_t)(b * NCH + c)) * T_SZ + t] = s;
    }
}

// ---------- energy kernel: r8 EXACT mechanics + masked-block early-exit ONLY ----------
// 8 waves x 16 rows (BM=128), 20x 16x16x32 MFMA per chunk per wave, BK=32 dbuf,
// reg->ds_write write-late staging, lgkmcnt-only barrier, all-LDS epilogue.
// DO NOT restructure this loop: r9/r10/r11 (gload_lds, 4x2 tiling, 32x32 MFMA)
// all collapsed occupancy (acc+VGPR crossing the 2-blocks/CU register boundary).
__global__ __launch_bounds__(512, 1) void energy_k(
    const float* __restrict__ enc, const unsigned short* __restrict__ wbf,
    const float* __restrict__ df, const float* __restrict__ att_conv,
    const float* __restrict__ W_att, const float* __restrict__ W_g,
    const int* __restrict__ len, float* __restrict__ e_out)
{
    __shared__ unsigned short sW[2][1280 * 8];    // 2 x 20 KB, granule-major (i = g*320+wr)
    __shared__ float sDf[ATT_DIM], sWg[ATT_DIM], sWatt[ATT_DIM * NCH], sConv[NCH * 128];

    int tid = threadIdx.x;
    int lane = tid & 63, wave = tid >> 6;         // 8 waves, BM=128
    int b = blockIdx.x >> 4;
    int t0 = (blockIdx.x & 15) << 7;

    // masked-block skip: softmax masks t >= len[b] by INDEX, e content irrelevant.
    // Exit precedes every barrier -> no sync hazard.
    if (t0 >= len[b]) return;

    int m15 = lane & 15, kg = lane >> 4;
    int row = t0 + wave * 16 + m15;
    const float* aP = enc + ((size_t)b * T_SZ + row) * EPROJS;

    // per-thread staging coords: granules tid, tid+512, (tid+1024 if tid<256)
    int q0 = tid >> 6;        int g0 = (q0 * 205) >> 10; int wr0 = tid - g0 * 320;
    int i1 = tid + 512;  int q1 = i1 >> 6; int g1 = (q1 * 205) >> 10; int wr1 = i1 - g1 * 320;
    int i2 = tid + 1024; int q2 = i2 >> 6; int g2 = (q2 * 205) >> 10; int wr2 = i2 - g2 * 320;
    bool do2 = tid < 256;
    const unsigned short* wp0 = wbf + (size_t)wr0 * EPROJS + g0 * 8;
    const unsigned short* wp1 = wbf + (size_t)wr1 * EPROJS + g1 * 8;
    const unsigned short* wp2 = wbf + (size_t)wr2 * EPROJS + g2 * 8;

    // ---- prologue: stage chunk 0 into buffer 0; A chunk 0 into regs ----
    {
        u16x8 v0 = *(const u16x8*)wp0;
        u16x8 v1 = *(const u16x8*)wp1;
        *(u16x8*)(&sW[0][tid * 8]) = v0;
        *(u16x8*)(&sW[0][i1 * 8]) = v1;
        if (do2) {
            u16x8 v2 = *(const u16x8*)wp2;
            *(u16x8*)(&sW[0][i2 * 8]) = v2;
        }
    }
    float4 a0 = *(const float4*)(aP + kg * 8);
    float4 a1 = *(const float4*)(aP + kg * 8 + 4);

    for (int i = tid; i < ATT_DIM; i += 512) { sDf[i] = df[b * ATT_DIM + i]; sWg[i] = W_g[i]; }
    for (int i = tid; i < ATT_DIM * NCH; i += 512) sWatt[i] = W_att[i];
    for (int i = tid; i < NCH * 128; i += 512)
        sConv[i] = att_conv[((size_t)(b * NCH + (i >> 7))) * T_SZ + t0 + (i & 127)];

    f32x4 acc[20];
    #pragma unroll
    for (int n = 0; n < 20; ++n) acc[n] = (f32x4){0.f, 0.f, 0.f, 0.f};

    __syncthreads();   // full drain once: chunk 0 + front matter visible

    for (int t = 0; t < 16; ++t) {
        int cur = t & 1;
        // 1) issue next chunk's W + A loads (wrap on last iter; harmless)
        int kn = ((t + 1) & 15) * 32;
        u16x8 w0 = *(const u16x8*)(wp0 + kn);
        u16x8 w1 = *(const u16x8*)(wp1 + kn);
        u16x8 w2;
        if (do2) w2 = *(const u16x8*)(wp2 + kn);
        float4 n0 = *(const float4*)(aP + kn + kg * 8);
        float4 n1 = *(const float4*)(aP + kn + kg * 8 + 4);

        // 2) compute chunk t from buf[cur]
        bf16x8 af;
        af[0] = (__bf16)a0.x; af[1] = (__bf16)a0.y; af[2] = (__bf16)a0.z; af[3] = (__bf16)a0.w;
        af[4] = (__bf16)a1.x; af[5] = (__bf16)a1.y; af[6] = (__bf16)a1.z; af[7] = (__bf16)a1.w;
        const unsigned short* sw = sW[cur];
        #pragma unroll
        for (int nt = 0; nt < 20; ++nt) {
            int wr = nt * 16 + m15;
            bf16x8 wf = *(const bf16x8*)(sw + (kg * 320 + wr) * 8);
            acc[nt] = __builtin_amdgcn_mfma_f32_16x16x32_bf16(af, wf, acc[nt], 0, 0, 0);
        }

        // 3) write-late: store next chunk into the other buffer
        unsigned short* swn = (unsigned short*)sW[cur ^ 1];
        *(u16x8*)(&swn[tid * 8]) = w0;
        *(u16x8*)(&swn[i1 * 8]) = w1;
        if (do2) *(u16x8*)(&swn[i2 * 8]) = w2;
        a0 = n0; a1 = n1;

        // 4) my ds ops complete -> barrier (NO vmcnt drain: A loads stay in flight)
        asm volatile("s_waitcnt lgkmcnt(0)" ::: "memory");
        __builtin_amdgcn_s_barrier();
    }

    // epilogue: e[t] = sum_a Wg[a] * tanh(acc + df[a] + att_feat[t,a]) — all LDS operands
    int tl_base = wave * 16 + kg * 4;
    #pragma unroll
    for (int r = 0; r < 4; ++r) {
        int tl = tl_base + r;
        float s = 0.f;
        #pragma unroll
        for (int nt = 0; nt < 20; ++nt) {
            int col = nt * 16 + m15;
            float v = acc[nt][r] + sDf[col];
            float afeat = 0.f;
            #pragma unroll
            for (int c = 0; c < NCH; ++c) afeat += sWatt[col * NCH + c] * sConv[c * 128 + tl];
            v += afeat;
            v = fminf(fmaxf(v, -15.f), 15.f);
            float e2 = __expf(2.f * v);
            s += sWg[col] * ((e2 - 1.f) / (e2 + 1.f));
        }
        s += __shfl_xor(s, 1); s += __shfl_xor(s, 2);
        s += __shfl_xor(s, 4); s += __shfl_xor(s, 8);
        if (m15 == 0) e_out[b * T_SZ + t0 + tl] = s;
    }
}

// ---------- masked softmax over T, per b ----------
__global__ void softmax_k(const float* __restrict__ e, const int* __restrict__ len,
                          float* __restrict__ w_out) {
    int b = blockIdx.x, tid = threadIdx.x;
    int lane = tid & 63, wave = tid >> 6;
    int L = len[b];
    float ev[8];
    float m = -1e30f;
    #pragma unroll
    for (int i = 0; i < 8; ++i) {
        int t = tid + i * 256;
        float x = e[b * T_SZ + t];
        if (t >= L) x = -1e30f;
        ev[i] = x;
        m = fmaxf(m, x);
    }
    #pragma unroll
    for (int o = 32; o > 0; o >>= 1) m = fmaxf(m, __shfl_xor(m, o));
    __shared__ float sred[4];
    if (lane == 0) sred[wave] = m;
    __syncthreads();
    m = fmaxf(fmaxf(sred[0], sred[1]), fmaxf(sred[2], sred[3]));

    float ex[8];
    float sum = 0.f;
    #pragma unroll
    for (int i = 0; i < 8; ++i) { ex[i] = __expf(2.f * (ev[i] - m)); sum += ex[i]; }
    #pragma unroll
    for (int o = 32; o > 0; o >>= 1) sum += __shfl_xor(sum, o);
    __shared__ float sred2[4];
    if (lane == 0) sred2[wave] = sum;
    __syncthreads();
    sum = sred2[0] + sred2[1] + sred2[2] + sred2[3];
    float inv = 1.f / sum;
    #pragma unroll
    for (int i = 0; i < 8; ++i) {
        int t = tid + i * 256;
        w_out[b * T_SZ + t] = ex[i] * inv;
    }
}

// ---------- context partial: branchless inner loop + masked-block skip ----------
__global__ void ctx_partial_k(const float* __restrict__ enc, const float* __restrict__ w,
                              const int* __restrict__ len, float* __restrict__ part) {
    int b = blockIdx.x, tc = blockIdx.y, tid = threadIdx.x;
    int half = tid >> 7;          // 0/1: even/odd rows
    int c4 = tid & 127;           // float4 column index (128*4 = 512)
    int tb = tc * 128;
    float* po = part + ((size_t)(b * 32 + tc * 2 + half)) * EPROJS + c4 * 4;
    if (tb >= len[b]) {           // whole chunk masked: contribute exact zeros
        *(f32x4*)po = (f32x4){0.f, 0.f, 0.f, 0.f};
        return;
    }
    f32x4 s = (f32x4){0.f, 0.f, 0.f, 0.f};
    #pragma unroll 4
    for (int i = half; i < 128; i += 2) {
        float wv = w[b * T_SZ + tb + i];              // masked rows are exactly 0
        f32x4 v = *(const f32x4*)(enc + ((size_t)b * T_SZ + tb + i) * EPROJS + c4 * 4);
        s += wv * v;
    }
    *(f32x4*)po = s;
}

__global__ void ctx_reduce_k(const float* __restrict__ part, float* __restrict__ c_out) {
    int b = blockIdx.x;
    int c4 = threadIdx.x;         // 128 threads, float4 each
    f32x4 s = (f32x4){0.f, 0.f, 0.f, 0.f};
    #pragma unroll
    for (int tc = 0; tc < 32; ++tc)
        s += *(const f32x4*)(part + ((size_t)(b * 32 + tc)) * EPROJS + c4 * 4);
    *(f32x4*)(c_out + b * EPROJS + c4 * 4) = s;
}

extern "C" void kernel_launch(void* const* d_in, const int* in_sizes, int n_in,
                              void* d_out, int out_size, void* d_ws, size_t ws_size,
                              hipStream_t stream) {
    const float* enc      = (const float*)d_in[0];
    const int*   len      = (const int*)d_in[1];
    const float* dec_z    = (const float*)d_in[2];
    const float* att_prev = (const float*)d_in[3];
    const float* W_enc    = (const float*)d_in[4];
    const float* b_enc    = (const float*)d_in[5];
    const float* W_dec    = (const float*)d_in[6];
    const float* W_att    = (const float*)d_in[7];
    const float* conv_w   = (const float*)d_in[8];
    const float* W_g      = (const float*)d_in[9];
    // b_g (d_in[10]) == 0 and softmax-invariant anyway.

    char* ws = (char*)d_ws;
    size_t off = 0;
    unsigned short* wbf = (unsigned short*)(ws + off); off += (size_t)ATT_DIM * EPROJS * 2;
    float* e_buf  = (float*)(ws + off); off += (size_t)B_SZ * T_SZ * 4;
    float* dfb    = (float*)(ws + off); off += (size_t)B_SZ * ATT_DIM * 4;
    float* att_cv = (float*)(ws + off); off += (size_t)B_SZ * NCH * T_SZ * 4;
    float* part   = (float*)(ws + off); off += (size_t)B_SZ * 32 * EPROJS * 4;

    float* c_out = (float*)d_out;                    // [64][512]
    float* w_out = (float*)d_out + B_SZ * EPROJS;    // [64][2048]

    cvt_wenc<<<dim3(160), dim3(256), 0, stream>>>(W_enc, wbf);
    dec_feat_k<<<dim3(B_SZ), dim3(ATT_DIM), 0, stream>>>(dec_z, W_dec, b_enc, dfb);
    conv_k<<<dim3(B_SZ, NCH), dim3(256), 0, stream>>>(att_prev, conv_w, att_cv);
    energy_k<<<dim3(B_SZ * 16), dim3(512), 0, stream>>>(enc, wbf, dfb, att_cv, W_att, W_g, len, e_buf);
    softmax_k<<<dim3(B_SZ), dim3(256), 0, stream>>>(e_buf, len, w_out);
    ctx_partial_k<<<dim3(B_SZ, 16), dim3(256), 0, stream>>>(enc, w_out, len, part);
    ctx_reduce_k<<<dim3(B_SZ), dim3(128), 0, stream>>>(part, c_out);
}

// Round 13
// 202.840 us; speedup vs baseline: 1.5157x; 1.2019x over previous
//
#include <hip/hip_runtime.h>
#include <hip/hip_bf16.h>

#define B_SZ 64
#define T_SZ 2048
#define EPROJS 512
#define DUNITS 1024
#define ATT_DIM 320
#define NCH 10
#define KFILT 201
#define PAD 100

typedef __attribute__((ext_vector_type(8))) __bf16 bf16x8;
typedef __attribute__((ext_vector_type(4))) float f32x4;
typedef __attribute__((ext_vector_type(8))) unsigned short u16x8;

__device__ __forceinline__ unsigned short f2b(float f) {
    __bf16 h = (__bf16)f;
    return __builtin_bit_cast(unsigned short, h);
}

// ---------- fused front kernel: cvt_wenc | dec_feat | conv (independent works) ----------
// blocks [0,160): W_enc f32->bf16 ; [160,240): dec_feat ; [240,880): conv
__global__ void front_k(const float* __restrict__ W_enc, unsigned short* __restrict__ wbf,
                        const float* __restrict__ dec_z, const float* __restrict__ W_dec,
                        const float* __restrict__ b_enc, float* __restrict__ df,
                        const float* __restrict__ ap, const float* __restrict__ cw,
                        float* __restrict__ conv_out)
{
    __shared__ float s_ap[T_SZ];
    __shared__ float s_cw[KFILT];
    int blk = blockIdx.x, tid = threadIdx.x;

    if (blk < 160) {                       // ---- cvt_wenc ----
        int i = (blk * 256 + tid) * 4;
        float4 v = *(const float4*)(W_enc + i);
        ushort4 o;
        o.x = f2b(v.x); o.y = f2b(v.y); o.z = f2b(v.z); o.w = f2b(v.w);
        *(ushort4*)(wbf + i) = o;
    } else if (blk < 240) {                // ---- dec_feat ----
        int idx = (blk - 160) * 256 + tid; // [0, 20480)
        int b = idx / ATT_DIM, a = idx - b * ATT_DIM;
        const float4* z = (const float4*)(dec_z + b * DUNITS);
        const float4* w = (const float4*)(W_dec + (size_t)a * DUNITS);
        float s = b_enc[a];
        #pragma unroll 4
        for (int d = 0; d < DUNITS / 4; ++d) {
            float4 zv = z[d], wv = w[d];
            s += zv.x * wv.x + zv.y * wv.y + zv.z * wv.z + zv.w * wv.w;
        }
        df[b * ATT_DIM + a] = s;
    } else {                               // ---- conv ----
        int cb = blk - 240;                // [0, 640)
        int b = cb / NCH, c = cb - b * NCH;
        for (int i = tid; i < T_SZ; i += 256) s_ap[i] = ap[b * T_SZ + i];
        for (int i = tid; i < KFILT; i += 256) s_cw[i] = cw[c * KFILT + i];
        __syncthreads();
        for (int j = 0; j < T_SZ / 256; ++j) {
            int t = tid + j * 256;
            int klo = max(0, PAD - t);
            int khi = min(KFILT, T_SZ + PAD - t);
            float s = 0.f;
            for (int k = klo; k < khi; ++k) s += s_ap[t - PAD + k] * s_cw[k];
            conv_out[((size_t)(b * NCH + c)) * T_SZ + t] = s;
        }
    }
}

// ---------- energy kernel: r8 mechanics + masked-block early-exit (r12, frozen) ----------
__global__ __launch_bounds__(512, 1) void energy_k(
    const float* __restrict__ enc, const unsigned short* __restrict__ wbf,
    const float* __restrict__ df, const float* __restrict__ att_conv,
    const float* __restrict__ W_att, const float* __restrict__ W_g,
    const int* __restrict__ len, float* __restrict__ e_out)
{
    __shared__ unsigned short sW[2][1280 * 8];    // 2 x 20 KB, granule-major (i = g*320+wr)
    __shared__ float sDf[ATT_DIM], sWg[ATT_DIM], sWatt[ATT_DIM * NCH], sConv[NCH * 128];

    int tid = threadIdx.x;
    int lane = tid & 63, wave = tid >> 6;         // 8 waves, BM=128
    int b = blockIdx.x >> 4;
    int t0 = (blockIdx.x & 15) << 7;

    if (t0 >= len[b]) return;   // masked tile: softmax masks by index, content irrelevant

    int m15 = lane & 15, kg = lane >> 4;
    int row = t0 + wave * 16 + m15;
    const float* aP = enc + ((size_t)b * T_SZ + row) * EPROJS;

    int q0 = tid >> 6;        int g0 = (q0 * 205) >> 10; int wr0 = tid - g0 * 320;
    int i1 = tid + 512;  int q1 = i1 >> 6; int g1 = (q1 * 205) >> 10; int wr1 = i1 - g1 * 320;
    int i2 = tid + 1024; int q2 = i2 >> 6; int g2 = (q2 * 205) >> 10; int wr2 = i2 - g2 * 320;
    bool do2 = tid < 256;
    const unsigned short* wp0 = wbf + (size_t)wr0 * EPROJS + g0 * 8;
    const unsigned short* wp1 = wbf + (size_t)wr1 * EPROJS + g1 * 8;
    const unsigned short* wp2 = wbf + (size_t)wr2 * EPROJS + g2 * 8;

    {
        u16x8 v0 = *(const u16x8*)wp0;
        u16x8 v1 = *(const u16x8*)wp1;
        *(u16x8*)(&sW[0][tid * 8]) = v0;
        *(u16x8*)(&sW[0][i1 * 8]) = v1;
        if (do2) {
            u16x8 v2 = *(const u16x8*)wp2;
            *(u16x8*)(&sW[0][i2 * 8]) = v2;
        }
    }
    float4 a0 = *(const float4*)(aP + kg * 8);
    float4 a1 = *(const float4*)(aP + kg * 8 + 4);

    for (int i = tid; i < ATT_DIM; i += 512) { sDf[i] = df[b * ATT_DIM + i]; sWg[i] = W_g[i]; }
    for (int i = tid; i < ATT_DIM * NCH; i += 512) sWatt[i] = W_att[i];
    for (int i = tid; i < NCH * 128; i += 512)
        sConv[i] = att_conv[((size_t)(b * NCH + (i >> 7))) * T_SZ + t0 + (i & 127)];

    f32x4 acc[20];
    #pragma unroll
    for (int n = 0; n < 20; ++n) acc[n] = (f32x4){0.f, 0.f, 0.f, 0.f};

    __syncthreads();

    for (int t = 0; t < 16; ++t) {
        int cur = t & 1;
        int kn = ((t + 1) & 15) * 32;
        u16x8 w0 = *(const u16x8*)(wp0 + kn);
        u16x8 w1 = *(const u16x8*)(wp1 + kn);
        u16x8 w2;
        if (do2) w2 = *(const u16x8*)(wp2 + kn);
        float4 n0 = *(const float4*)(aP + kn + kg * 8);
        float4 n1 = *(const float4*)(aP + kn + kg * 8 + 4);

        bf16x8 af;
        af[0] = (__bf16)a0.x; af[1] = (__bf16)a0.y; af[2] = (__bf16)a0.z; af[3] = (__bf16)a0.w;
        af[4] = (__bf16)a1.x; af[5] = (__bf16)a1.y; af[6] = (__bf16)a1.z; af[7] = (__bf16)a1.w;
        const unsigned short* sw = sW[cur];
        #pragma unroll
        for (int nt = 0; nt < 20; ++nt) {
            int wr = nt * 16 + m15;
            bf16x8 wf = *(const bf16x8*)(sw + (kg * 320 + wr) * 8);
            acc[nt] = __builtin_amdgcn_mfma_f32_16x16x32_bf16(af, wf, acc[nt], 0, 0, 0);
        }

        unsigned short* swn = (unsigned short*)sW[cur ^ 1];
        *(u16x8*)(&swn[tid * 8]) = w0;
        *(u16x8*)(&swn[i1 * 8]) = w1;
        if (do2) *(u16x8*)(&swn[i2 * 8]) = w2;
        a0 = n0; a1 = n1;

        asm volatile("s_waitcnt lgkmcnt(0)" ::: "memory");
        __builtin_amdgcn_s_barrier();
    }

    int tl_base = wave * 16 + kg * 4;
    #pragma unroll
    for (int r = 0; r < 4; ++r) {
        int tl = tl_base + r;
        float s = 0.f;
        #pragma unroll
        for (int nt = 0; nt < 20; ++nt) {
            int col = nt * 16 + m15;
            float v = acc[nt][r] + sDf[col];
            float afeat = 0.f;
            #pragma unroll
            for (int c = 0; c < NCH; ++c) afeat += sWatt[col * NCH + c] * sConv[c * 128 + tl];
            v += afeat;
            v = fminf(fmaxf(v, -15.f), 15.f);
            float e2 = __expf(2.f * v);
            s += sWg[col] * ((e2 - 1.f) / (e2 + 1.f));
        }
        s += __shfl_xor(s, 1); s += __shfl_xor(s, 2);
        s += __shfl_xor(s, 4); s += __shfl_xor(s, 8);
        if (m15 == 0) e_out[b * T_SZ + t0 + tl] = s;
    }
}

// ---------- fused softmax + context partial ----------
// Each (b,tc) block recomputes row softmax stats (cheap, e_buf L2-hot), writes its
// w slice, and accumulates the weighted enc sum for its 128 rows.
__global__ void softmax_ctx_k(const float* __restrict__ e, const int* __restrict__ len,
                              const float* __restrict__ enc,
                              float* __restrict__ w_out, float* __restrict__ part) {
    int b = blockIdx.x, tc = blockIdx.y, tid = threadIdx.x;
    int lane = tid & 63, wave = tid >> 6;
    int L = len[b];
    int tb = tc * 128;
    int half = tid >> 7;          // 0/1: even/odd rows
    int c4 = tid & 127;           // float4 column index
    float* po = part + ((size_t)(b * 32 + tc * 2 + half)) * EPROJS + c4 * 4;

    if (tb >= L) {                // fully masked tile: exact zeros, no stats needed
        if (tid < 128) w_out[b * T_SZ + tb + tid] = 0.f;
        *(f32x4*)po = (f32x4){0.f, 0.f, 0.f, 0.f};
        return;
    }

    // --- softmax stats over the full row (masked by index) ---
    float ev[8];
    float m = -1e30f;
    #pragma unroll
    for (int i = 0; i < 8; ++i) {
        int t = tid + i * 256;
        float x = e[b * T_SZ + t];
        if (t >= L) x = -1e30f;
        ev[i] = x;
        m = fmaxf(m, x);
    }
    #pragma unroll
    for (int o = 32; o > 0; o >>= 1) m = fmaxf(m, __shfl_xor(m, o));
    __shared__ float sred[4];
    if (lane == 0) sred[wave] = m;
    __syncthreads();
    m = fmaxf(fmaxf(sred[0], sred[1]), fmaxf(sred[2], sred[3]));

    float sum = 0.f;
    #pragma unroll
    for (int i = 0; i < 8; ++i) sum += __expf(2.f * (ev[i] - m));   // masked -> exp(-inf)=0
    #pragma unroll
    for (int o = 32; o > 0; o >>= 1) sum += __shfl_xor(sum, o);
    __shared__ float sred2[4];
    if (lane == 0) sred2[wave] = sum;
    __syncthreads();
    sum = sred2[0] + sred2[1] + sred2[2] + sred2[3];
    float inv = 1.f / sum;

    // --- write this tile's w slice ---
    if (tid < 128) {
        int t = tb + tid;
        float wv = 0.f;
        if (t < L) wv = __expf(2.f * (e[b * T_SZ + t] - m)) * inv;
        w_out[b * T_SZ + t] = wv;
    }

    // --- weighted enc sum for this tile (branchless inner loop) ---
    f32x4 s = (f32x4){0.f, 0.f, 0.f, 0.f};
    #pragma unroll 4
    for (int i = half; i < 128; i += 2) {
        int t = tb + i;
        float ee = e[b * T_SZ + t];
        float wv = (t < L) ? __expf(2.f * (ee - m)) * inv : 0.f;
        f32x4 v = *(const f32x4*)(enc + ((size_t)b * T_SZ + t) * EPROJS + c4 * 4);
        s += wv * v;
    }
    *(f32x4*)po = s;
}

__global__ void ctx_reduce_k(const float* __restrict__ part, float* __restrict__ c_out) {
    int b = blockIdx.x;
    int c4 = threadIdx.x;         // 128 threads, float4 each
    f32x4 s = (f32x4){0.f, 0.f, 0.f, 0.f};
    #pragma unroll
    for (int tc = 0; tc < 32; ++tc)
        s += *(const f32x4*)(part + ((size_t)(b * 32 + tc)) * EPROJS + c4 * 4);
    *(f32x4*)(c_out + b * EPROJS + c4 * 4) = s;
}

extern "C" void kernel_launch(void* const* d_in, const int* in_sizes, int n_in,
                              void* d_out, int out_size, void* d_ws, size_t ws_size,
                              hipStream_t stream) {
    const float* enc      = (const float*)d_in[0];
    const int*   len      = (const int*)d_in[1];
    const float* dec_z    = (const float*)d_in[2];
    const float* att_prev = (const float*)d_in[3];
    const float* W_enc    = (const float*)d_in[4];
    const float* b_enc    = (const float*)d_in[5];
    const float* W_dec    = (const float*)d_in[6];
    const float* W_att    = (const float*)d_in[7];
    const float* conv_w   = (const float*)d_in[8];
    const float* W_g      = (const float*)d_in[9];
    // b_g (d_in[10]) == 0 and softmax-invariant anyway.

    char* ws = (char*)d_ws;
    size_t off = 0;
    unsigned short* wbf = (unsigned short*)(ws + off); off += (size_t)ATT_DIM * EPROJS * 2;
    float* e_buf  = (float*)(ws + off); off += (size_t)B_SZ * T_SZ * 4;
    float* dfb    = (float*)(ws + off); off += (size_t)B_SZ * ATT_DIM * 4;
    float* att_cv = (float*)(ws + off); off += (size_t)B_SZ * NCH * T_SZ * 4;
    float* part   = (float*)(ws + off); off += (size_t)B_SZ * 32 * EPROJS * 4;

    float* c_out = (float*)d_out;                    // [64][512]
    float* w_out = (float*)d_out + B_SZ * EPROJS;    // [64][2048]

    front_k<<<dim3(880), dim3(256), 0, stream>>>(W_enc, wbf, dec_z, W_dec, b_enc, dfb,
                                                 att_prev, conv_w, att_cv);
    energy_k<<<dim3(B_SZ * 16), dim3(512), 0, stream>>>(enc, wbf, dfb, att_cv, W_att, W_g, len, e_buf);
    softmax_ctx_k<<<dim3(B_SZ, 16), dim3(256), 0, stream>>>(e_buf, len, enc, w_out, part);
    ctx_reduce_k<<<dim3(B_SZ), dim3(128), 0, stream>>>(part, c_out);
}